// Round 3
// baseline (2654.972 us; speedup 1.0000x reference)
//
#include <hip/hip_runtime.h>
#include <hip/hip_fp16.h>
#include <math.h>

#define BB 128
#define SS 512
#define TT 128
#define FF 64
#define HH 1024

#define NBT 8      // batch groups, M=16 each (independent barrier domains)
#define NJB 32     // j-blocks, N=128 each (4 gates x 32 j)
#define NBLK 256
#define NTHR 256   // 4 waves = 4 k-quarters (K=256), full N=128 per wave

typedef _Float16 half8 __attribute__((ext_vector_type(8)));
typedef float    f32x4 __attribute__((ext_vector_type(4)));
typedef unsigned uint4v __attribute__((ext_vector_type(4)));
typedef unsigned long long u64;

// ---- fast transcendentals (rel err ~1e-6 << fp16 noise floor) ----
__device__ __forceinline__ float rcpf(float x){ return __builtin_amdgcn_rcpf(x); }
__device__ __forceinline__ float sigm(float x){ return rcpf(1.f + __expf(-x)); }
__device__ __forceinline__ float tfast(float x){
  float a = fabsf(x);
  float e = __expf(-2.f*a);
  float t = (1.f - e) * rcpf(1.f + e);
  return copysignf(t, x);
}

// ---- agent (IF$) scope: sc1, cross-XCD coherent (PROVEN baseline mechanism) ----
__device__ __forceinline__ u64 aload64(const u64* p){
  return __hip_atomic_load(p, __ATOMIC_RELAXED, __HIP_MEMORY_SCOPE_AGENT);
}
__device__ __forceinline__ float aloadf(const float* p){
  return __hip_atomic_load(p, __ATOMIC_RELAXED, __HIP_MEMORY_SCOPE_AGENT);
}
__device__ __forceinline__ unsigned aloadu(const unsigned* p){
  return __hip_atomic_load(p, __ATOMIC_RELAXED, __HIP_MEMORY_SCOPE_AGENT);
}
__device__ __forceinline__ void astoref(float* p, float v){
  __hip_atomic_store(p, v, __ATOMIC_RELAXED, __HIP_MEMORY_SCOPE_AGENT);
}
__device__ __forceinline__ void astoreu(unsigned* p, unsigned v){
  __hip_atomic_store(p, v, __ATOMIC_RELAXED, __HIP_MEMORY_SCOPE_AGENT);
}

// ---- XCD-local DATA ops: sc0 = bypass L1, coherence point = per-XCD L2.
// Used ONLY for bulk data (h, pred) on verified-uniform XCDs; NEVER for spins.
__device__ __forceinline__ void stu_sc0(unsigned* p, unsigned v){
  asm volatile("global_store_dword %0, %1, off sc0" :: "v"(p), "v"(v) : "memory");
}
__device__ __forceinline__ void stf_sc0(float* p, float v){
  asm volatile("global_store_dword %0, %1, off sc0" :: "v"(p), "v"(v) : "memory");
}
// issue-only (NO waitcnt): drained by a later volatile-asm vmcnt(0); outputs
// consumed only after the reuse-fence asm (guide rule #18).
__device__ __forceinline__ void ld2f_issue_sc0(const float* p0, const float* p1,
                                               float& a, float& b){
  asm volatile("global_load_dword %0, %2, off sc0\n\t"
               "global_load_dword %1, %3, off sc0"
               : "=&v"(a), "=&v"(b) : "v"(p0), "v"(p1) : "memory");
}

// ---- barriers (per btile: 32 flags) — flags ALWAYS agent/sc1 (baseline-proven) ----
__device__ __forceinline__ void bar_arrive(unsigned* flags, int jblk, unsigned* barno){
  asm volatile("s_waitcnt vmcnt(0)" ::: "memory");  // data stores ack'd at coherence pt
  __syncthreads();
  ++(*barno);
  if (threadIdx.x == 0) astoreu(&flags[jblk], *barno);
}
__device__ __forceinline__ void bar_wait_full(const unsigned* flags, unsigned barno){
  if (threadIdx.x < 32){
    while (__hip_atomic_load(&flags[threadIdx.x], __ATOMIC_RELAXED,
                             __HIP_MEMORY_SCOPE_AGENT) < barno) {}
  }
  __syncthreads();
}
// encoder: wave wk consumes only producers jblk'=8wk..8wk+7 (its K-slice).
// No __syncthreads: cross-wave LDS ordering is provided by bar_arrive's sync.
__device__ __forceinline__ void bar_wait_wave8(const unsigned* flags, unsigned barno, int wk){
  int ll = threadIdx.x & 63;
  if (ll < 8){
    while (__hip_atomic_load(&flags[wk*8 + ll], __ATOMIC_RELAXED,
                             __HIP_MEMORY_SCOPE_AGENT) < barno) {}
  }
  __builtin_amdgcn_sched_barrier(0);  // keep volatile data loads behind the spin
}

// ---- pre-kernels: fp32 -> fp16 ----
__global__ __launch_bounds__(256) void cvt_plain(const float* __restrict__ s,
                                                 ushort* __restrict__ d, int n){
  for (int i = blockIdx.x*256 + threadIdx.x; i < n; i += gridDim.x*256)
    d[i] = __half_as_ushort(__float2half(s[i]));
}
// src [b][s][f] -> src16T [s][f>>3][b][f&7]
__global__ __launch_bounds__(256) void cvt_src(const float* __restrict__ s,
                                               ushort* __restrict__ d){
  for (int i = blockIdx.x*256 + threadIdx.x; i < BB*SS*FF; i += gridDim.x*256){
    int f = i & 63, st = (i >> 6) & 511, b = i >> 15;
    d[(((size_t)st*8 + (f>>3))*128 + b)*8 + (f&7)] = __half_as_ushort(__float2half(s[i]));
  }
}

// h slots (btile-major: each (parity,btile) slab = contiguous 32KB, stays in one
// XCD's L2 in LOC mode):  ushort h16[2][btile=8][o=128][b16=16][8]   (o = j>>3)
// pred: float ppsl[2][8 btile][32 jblk][16 m]
template<bool LOC>
__device__ __forceinline__ void run_loop(
  int tid, int btile, int jblk, unsigned barno,
  const float* __restrict__ tgt,
  const _Float16* __restrict__ src16T,
  const _Float16* __restrict__ dwhh16,
  const float* __restrict__ dWih,
  const float* __restrict__ dbih, const float* __restrict__ dbhh,
  const float* __restrict__ fcW, float fcb0v,
  float* __restrict__ out, ushort* __restrict__ h16u,
  float* __restrict__ ppsl, unsigned* __restrict__ flags,
  half8 (&Bh)[64], const half8 (&Bx)[8],
  float (&ebv)[8], float (&wxv)[8], float (&fcwv)[2],
  float (&Ct4)[4][16][132], float (&xacc)[2][16], float (&predsum)[16])
{
  const int wk = tid >> 6;               // k-quarter (K=256)
  const int l  = tid & 63;
  const int la = l & 15, lq = l >> 4;    // frag: row/col-in-tile, k-octet-quarter
  const int m = tid & 15, q = tid >> 4;  // epilogue: (b=m, j-pair 2q,2q+1)
  float cc0 = 0.f, cc1 = 0.f;            // cell state in registers for all 639 steps

  for (int t = 0; t < SS + TT - 1; t++){
    const bool enc = (t < SS);
    f32x4 acc[8];
    #pragma unroll
    for (int nt = 0; nt < 8; nt++)
      #pragma unroll
      for (int r = 0; r < 4; r++) acc[nt][r] = 0.f;

    if (t == SS){   // decoder switch (in-register)
      #pragma unroll
      for (int kc = 0; kc < 8; kc++)
        #pragma unroll
        for (int nt = 0; nt < 8; nt++){
          size_t grow = (size_t)((nt>>1)*HH + jblk*32 + (nt&1)*16 + la);
          Bh[kc*8+nt] = *(const half8*)(dwhh16 + grow*HH + wk*256 + kc*32 + lq*8);
        }
      #pragma unroll
      for (int g = 0; g < 4; g++)
        #pragma unroll
        for (int u = 0; u < 2; u++){
          int jg = jblk*32 + 2*q + u;
          ebv[g*2+u] = dbih[g*HH + jg] + dbhh[g*HH + jg];
          wxv[g*2+u] = dWih[g*HH + jg];
        }
      fcwv[0] = fcW[jblk*32 + 2*q];
      fcwv[1] = fcW[jblk*32 + 2*q + 1];
    }

    // encoder x-part (waves 0,1 each K=32) before the wait
    if (enc && wk < 2){
      half8 xa = *(const half8*)(src16T +
                   (((size_t)t*8 + wk*4 + lq)*128 + btile*16 + la)*8);
      #pragma unroll
      for (int nt = 0; nt < 8; nt++)
        acc[nt] = __builtin_amdgcn_mfma_f32_16x16x32_f16(xa, Bx[nt], acc[nt], 0,0,0);
    }

    // wave-local wait while only h is consumed; full wait once pred is needed
    if (t <= SS) bar_wait_wave8(flags, barno, wk);
    else         bar_wait_full(flags, barno);

    float pv0 = 0.f, pv1 = 0.f;
    const bool haspred = (!enc && t > SS);
    if (haspred){   // pred partial loads (latency hidden under h loads)
      const float* pp = ppsl + ((size_t)(((t+1)&1)*NBT + btile)*NJB)*16;
      if constexpr (LOC){
        ld2f_issue_sc0(pp + (size_t)q*16 + m, pp + (size_t)(q+16)*16 + m, pv0, pv1);
      } else {
        pv0 = aloadf(pp + (size_t)q*16 + m);
        pv1 = aloadf(pp + (size_t)(q+16)*16 + m);
      }
    }

    // ---- h K-loop: L2(sc0) / IF$(sc1) loads -> MFMA, no LDS, no syncs ----
    if (t > 0){
      const ushort* hb = h16u + ((size_t)((t&1)*8 + btile))*16384
                       + (size_t)wk*4096 + (size_t)lq*128 + (size_t)la*8;
      if constexpr (LOC){
        uint4v hv[8];
        asm volatile(
          "global_load_dwordx4 %0, %8, off sc0\n\t"
          "global_load_dwordx4 %1, %8, off offset:1024 sc0\n\t"
          "global_load_dwordx4 %2, %8, off offset:2048 sc0\n\t"
          "global_load_dwordx4 %3, %8, off offset:3072 sc0\n\t"
          "global_load_dwordx4 %4, %9, off sc0\n\t"
          "global_load_dwordx4 %5, %9, off offset:1024 sc0\n\t"
          "global_load_dwordx4 %6, %9, off offset:2048 sc0\n\t"
          "global_load_dwordx4 %7, %9, off offset:3072 sc0\n\t"
          "s_waitcnt vmcnt(0)"
          : "=&v"(hv[0]), "=&v"(hv[1]), "=&v"(hv[2]), "=&v"(hv[3]),
            "=&v"(hv[4]), "=&v"(hv[5]), "=&v"(hv[6]), "=&v"(hv[7])
          : "v"(hb), "v"(hb + 2048)
          : "memory");
        __builtin_amdgcn_sched_barrier(0);
        #pragma unroll
        for (int kc = 0; kc < 8; kc++){
          union { uint4v u; half8 h; } ua; ua.u = hv[kc];
          #pragma unroll
          for (int nt = 0; nt < 8; nt++)
            acc[nt] = __builtin_amdgcn_mfma_f32_16x16x32_f16(ua.h, Bh[kc*8+nt], acc[nt], 0,0,0);
        }
      } else {
        u64 w0[8], w1[8];
        #pragma unroll
        for (int kc = 0; kc < 8; kc++){
          const u64* p = (const u64*)(hb + (size_t)kc*512);
          w0[kc] = aload64(p); w1[kc] = aload64(p+1);
        }
        #pragma unroll
        for (int kc = 0; kc < 8; kc++){
          union { u64 qq[2]; half8 v; } ua;
          ua.qq[0] = w0[kc]; ua.qq[1] = w1[kc];
          #pragma unroll
          for (int nt = 0; nt < 8; nt++)
            acc[nt] = __builtin_amdgcn_mfma_f32_16x16x32_f16(ua.v, Bh[kc*8+nt], acc[nt], 0,0,0);
        }
      }
    }

    if constexpr (LOC){
      // ordering fence: pred regs valid only after the h-asm's vmcnt(0)
      if (haspred) asm volatile("" : "+v"(pv0), "+v"(pv1));
    }

    // ---- epilogue: 4-way k-reduce + gate transpose through LDS ----
    if (tid < 16) predsum[tid] = 0.f;
    if (tid >= 16 && tid < 32) xacc[(t+1)&1][tid-16] = 0.f;
    #pragma unroll
    for (int nt = 0; nt < 8; nt++)
      #pragma unroll
      for (int r = 0; r < 4; r++)
        Ct4[wk][lq*4 + r][nt*16 + la] = acc[nt][r];   // 16x16 C/D: col=la, row=lq*4+r
    float xr = 0.f;
    if (!enc){
      if (t == SS) xr = tgt[(size_t)(btile*16 + m)*TT];
      else atomicAdd(&xacc[t&1][m], pv0 + pv1);
    }
    __syncthreads();
    if (!enc && t > SS){
      xr = xacc[t&1][m] + fcb0v;
      if (jblk == 0 && tid < 16)
        out[(size_t)(btile*16 + tid)*TT + (t - SS)] = xacc[t&1][tid] + fcb0v;
    }

    float gv[8];
    #pragma unroll
    for (int g = 0; g < 4; g++)
      #pragma unroll
      for (int u = 0; u < 2; u++){
        int n = g*32 + 2*q + u;
        float s2 = ((Ct4[0][m][n] + Ct4[1][m][n]) + (Ct4[2][m][n] + Ct4[3][m][n]))
                 + ebv[g*2+u];
        if (!enc) s2 += xr * wxv[g*2+u];
        gv[g*2+u] = s2;
      }
    float h2[2];
    #pragma unroll
    for (int u = 0; u < 2; u++){
      float si = sigm(gv[0+u]), sf = sigm(gv[2+u]), so = sigm(gv[6+u]);
      float tg = tfast(gv[4+u]);
      float c = u ? cc1 : cc0;
      c = sf*c + si*tg;
      if (u) cc1 = c; else cc0 = c;
      h2[u] = so * tfast(c);
    }
    {  // h(t+1) store: packed dword (j=2q,2q+1 adjacent in 16B slot)
      int o = jblk*4 + (q >> 2);
      unsigned hvw = (unsigned)__half_as_ushort(__float2half(h2[0]))
                   | ((unsigned)__half_as_ushort(__float2half(h2[1])) << 16);
      unsigned* hp = (unsigned*)(h16u + ((size_t)(((t+1)&1)*8 + btile))*16384
                                 + ((size_t)o*16 + m)*8 + (q&3)*2);
      if constexpr (LOC) stu_sc0(hp, hvw); else astoreu(hp, hvw);
    }
    if (!enc){
      atomicAdd(&predsum[m], h2[0]*fcwv[0] + h2[1]*fcwv[1]);
      __syncthreads();
      if (tid < 16){
        float* pps = ppsl + (((size_t)(t&1)*NBT + btile)*NJB + jblk)*16 + tid;
        if constexpr (LOC) stf_sc0(pps, predsum[tid]); else astoref(pps, predsum[tid]);
      }
    }
    bar_arrive(flags, jblk, &barno);   // vmcnt-drain (L2 in LOC, IF$ in fallback)
  }

  // ---- final column 127 = fc(h(127)): pred of t=638 at parity 0 ----
  if (jblk == 0){
    bar_wait_full(flags, barno);
    const float* pp = ppsl + ((size_t)btile*NJB)*16;
    float a, b;
    if constexpr (LOC){
      ld2f_issue_sc0(pp + (size_t)q*16 + m, pp + (size_t)(q+16)*16 + m, a, b);
      asm volatile("s_waitcnt vmcnt(0)" ::: "memory");
      asm volatile("" : "+v"(a), "+v"(b));
    } else {
      a = aloadf(pp + (size_t)q*16 + m);
      b = aloadf(pp + (size_t)(q+16)*16 + m);
    }
    atomicAdd(&xacc[1][m], a + b);        // zeroed during t=638
    __syncthreads();
    if (tid < 16)
      out[(size_t)(btile*16 + tid)*TT + (TT-1)] = xacc[1][tid] + fcb0v;
  }
}

__global__ __launch_bounds__(NTHR, 1) void seq_kernel(
  const float*  __restrict__ tgt,
  const _Float16* __restrict__ src16T,  // [512][8][128][8]
  const _Float16* __restrict__ wih16,   // [4H][64]
  const _Float16* __restrict__ ewhh16,  // [4H][1024]
  const _Float16* __restrict__ dwhh16,  // [4H][1024]
  const float* __restrict__ ebih, const float* __restrict__ ebhh,
  const float* __restrict__ dWih,
  const float* __restrict__ dbih, const float* __restrict__ dbhh,
  const float* __restrict__ fcW, const float* __restrict__ fcb,
  float* __restrict__ out, ushort* h16u, float* ppsl, unsigned* barflags,
  unsigned* xcdtab)
{
  __shared__ float Ct4[4][16][132];  // [wk][m][n], pad 132: <=2-way bank alias (free)
  __shared__ float xacc[2][16];
  __shared__ float predsum[16];
  __shared__ int s_loc;

  const int tid = threadIdx.x;
  const int wk  = tid >> 6;
  const int l   = tid & 63;
  const int la  = l & 15, lq = l >> 4;
  // co-locate each btile's 32 jblks on one XCD (bid%8 -> XCD heuristic; VERIFIED
  // below via HW_REG_XCC_ID ballot — sc0 data path only engages if uniform)
  const int btile = blockIdx.x & 7;
  const int jblk  = blockIdx.x >> 3;
  const int q = tid >> 4;

  // ---- B fragments to registers: Bh[kc*8+nt], kc=k-chunk(32) in wave, nt=n-tile ----
  half8 Bh[64];
  #pragma unroll
  for (int kc = 0; kc < 8; kc++)
    #pragma unroll
    for (int nt = 0; nt < 8; nt++){
      size_t grow = (size_t)((nt>>1)*HH + jblk*32 + (nt&1)*16 + la);
      Bh[kc*8+nt] = *(const half8*)(ewhh16 + grow*HH + wk*256 + kc*32 + lq*8);
    }
  half8 Bx[8];
  if (wk < 2)
    #pragma unroll
    for (int nt = 0; nt < 8; nt++){
      size_t grow = (size_t)((nt>>1)*HH + jblk*32 + (nt&1)*16 + la);
      Bx[nt] = *(const half8*)(wih16 + grow*FF + wk*32 + lq*8);
    }

  float ebv[8], wxv[8], fcwv[2];
  #pragma unroll
  for (int g = 0; g < 4; g++)
    #pragma unroll
    for (int u = 0; u < 2; u++){
      int jg = jblk*32 + 2*q + u;
      ebv[g*2+u] = ebih[g*HH + jg] + ebhh[g*HH + jg];
      wxv[g*2+u] = 0.f;
    }
  fcwv[0] = fcwv[1] = 0.f;
  const float fcb0v = fcb[0];

  if (jblk == 0 && tid < 16) out[(size_t)(btile*16 + tid)*TT] = 0.f;

  // ---- publish XCC_ID, then the NORMAL initial barrier (no new spin surface:
  // the arrive's vmcnt(0) drains the publish; wait #1 is the baseline pattern) ----
  unsigned xcc;
  asm volatile("s_getreg_b32 %0, hwreg(HW_REG_XCC_ID)" : "=s"(xcc));
  if (tid == 0) astoreu(&xcdtab[btile*NJB + jblk], xcc + 1u);

  unsigned* flags = barflags + btile*NJB;
  unsigned barno = 0;
  bar_arrive(flags, jblk, &barno);      // -> flag #1 (covers xcdtab publish)
  bar_wait_full(flags, barno);          // all 32 peers arrived -> entries visible

  if (tid < 64){
    unsigned ent = 1u;
    if (tid < NJB) ent = aloadu(&xcdtab[btile*NJB + tid]);
    unsigned ref = __shfl(ent, 0, 64);
    bool ok = (tid < NJB) ? (ent == ref && ent != 0u) : true;
    unsigned long long bal = __ballot(ok);
    if (tid == 0) s_loc = (bal == ~0ull) ? 1 : 0;
  }
  __syncthreads();

  if (s_loc)
    run_loop<true >(tid, btile, jblk, barno, tgt, src16T, dwhh16, dWih, dbih, dbhh,
                    fcW, fcb0v, out, h16u, ppsl, flags, Bh, Bx, ebv, wxv, fcwv,
                    Ct4, xacc, predsum);
  else
    run_loop<false>(tid, btile, jblk, barno, tgt, src16T, dwhh16, dWih, dbih, dbhh,
                    fcW, fcb0v, out, h16u, ppsl, flags, Bh, Bx, ebv, wxv, fcwv,
                    Ct4, xacc, predsum);
}

extern "C" void kernel_launch(void* const* d_in, const int* in_sizes, int n_in,
                              void* d_out, int out_size, void* d_ws, size_t ws_size,
                              hipStream_t stream){
  (void)in_sizes; (void)n_in; (void)out_size; (void)ws_size;
  const float* src  = (const float*)d_in[0];
  const float* tgt  = (const float*)d_in[1];
  const float* eWih = (const float*)d_in[2];
  const float* eWhh = (const float*)d_in[3];
  const float* ebih = (const float*)d_in[4];
  const float* ebhh = (const float*)d_in[5];
  const float* dWih = (const float*)d_in[6];
  const float* dWhh = (const float*)d_in[7];
  const float* dbih = (const float*)d_in[8];
  const float* dbhh = (const float*)d_in[9];
  const float* fcW  = (const float*)d_in[10];
  const float* fcb  = (const float*)d_in[11];
  float* out = (float*)d_out;

  // ws carve (ushort units)
  ushort* h16    = (ushort*)d_ws;          // 2*8*128*16*8     = 262144
  ushort* src16T = h16    + 262144;        // 512*8*128*8      = 4194304
  ushort* wih16  = src16T + 4194304;       // 4096*64          = 262144
  ushort* ewhh16 = wih16  + 262144;        // 4096*1024        = 4194304
  ushort* dwhh16 = ewhh16 + 4194304;       // 4096*1024        = 4194304
  float*  ppsl   = (float*)(dwhh16 + 4194304);     // 2*8*32*16 = 8192 floats
  unsigned* barflags = (unsigned*)(ppsl + 8192);   // 8 btiles x 32 u32
  unsigned* xcdtab   = barflags + NBT*NJB;         // 8 x 32 u32

  hipMemsetAsync(barflags, 0, 2*NBT*NJB*sizeof(unsigned), stream);
  cvt_src  <<<4096, 256, 0, stream>>>(src, src16T);
  cvt_plain<<<1024, 256, 0, stream>>>(eWih, wih16,  4*HH*FF);
  cvt_plain<<<4096, 256, 0, stream>>>(eWhh, ewhh16, 4*HH*HH);
  cvt_plain<<<4096, 256, 0, stream>>>(dWhh, dwhh16, 4*HH*HH);
  seq_kernel<<<dim3(NBLK), dim3(NTHR), 0, stream>>>(
      tgt, (const _Float16*)src16T, (const _Float16*)wih16,
      (const _Float16*)ewhh16, (const _Float16*)dwhh16,
      ebih, ebhh, dWih, dbih, dbhh, fcW, fcb, out, h16, ppsl, barflags,
      xcdtab);
}

// Round 5
// 2643.718 us; speedup vs baseline: 1.0043x; 1.0043x over previous
//
#include <hip/hip_runtime.h>
#include <hip/hip_fp16.h>
#include <math.h>

#define BB 128
#define SS 512
#define TT 128
#define FF 64
#define HH 1024

#define NBT 8      // batch groups, M=16 each (independent barrier domains)
#define NJB 32     // j-blocks, N=128 each (4 gates x 32 j)
#define NBLK 256
#define NTHR 256   // 4 waves = 4 k-quarters (K=256), full N=128 per wave

typedef _Float16 half8 __attribute__((ext_vector_type(8)));
typedef float    f32x4 __attribute__((ext_vector_type(4)));
typedef unsigned uint4v __attribute__((ext_vector_type(4)));
typedef unsigned long long u64;

// ---- fast transcendentals (rel err ~1e-6 << fp16 noise floor) ----
__device__ __forceinline__ float rcpf(float x){ return __builtin_amdgcn_rcpf(x); }
__device__ __forceinline__ float sigm(float x){ return rcpf(1.f + __expf(-x)); }
__device__ __forceinline__ float tfast(float x){
  float a = fabsf(x);
  float e = __expf(-2.f*a);
  float t = (1.f - e) * rcpf(1.f + e);
  return copysignf(t, x);
}

// ---- agent (IF$) scope: sc1, cross-XCD coherent (baseline-proven) ----
__device__ __forceinline__ u64 aload64(const u64* p){
  return __hip_atomic_load(p, __ATOMIC_RELAXED, __HIP_MEMORY_SCOPE_AGENT);
}
__device__ __forceinline__ float aloadf(const float* p){
  return __hip_atomic_load(p, __ATOMIC_RELAXED, __HIP_MEMORY_SCOPE_AGENT);
}
__device__ __forceinline__ unsigned aloadu(const unsigned* p){
  return __hip_atomic_load(p, __ATOMIC_RELAXED, __HIP_MEMORY_SCOPE_AGENT);
}
__device__ __forceinline__ void astoref(float* p, float v){
  __hip_atomic_store(p, v, __ATOMIC_RELAXED, __HIP_MEMORY_SCOPE_AGENT);
}
__device__ __forceinline__ void astoreu(unsigned* p, unsigned v){
  __hip_atomic_store(p, v, __ATOMIC_RELAXED, __HIP_MEMORY_SCOPE_AGENT);
}

// ---- XCD-local DATA ops: sc0 = bypass L1, coherence point = per-XCD L2.
// r3 evidence: 639 steps of cross-block h deps bit-correct via sc0 ld/st.
// Used ONLY for one-shot bulk data after a proven barrier; NEVER for spins
// (sc0 spins hung in r1/r2/r4 — mechanism unknown, empirically fatal).
__device__ __forceinline__ void stu_sc0(unsigned* p, unsigned v){
  asm volatile("global_store_dword %0, %1, off sc0" :: "v"(p), "v"(v) : "memory");
}
__device__ __forceinline__ void stf_sc0(float* p, float v){
  asm volatile("global_store_dword %0, %1, off sc0" :: "v"(p), "v"(v) : "memory");
}
// issue-only (NO waitcnt): drained by a later volatile-asm vmcnt(0); outputs
// consumed only after the reuse-fence asm (guide rule #18).
__device__ __forceinline__ void ld2f_issue_sc0(const float* p0, const float* p1,
                                               float& a, float& b){
  asm volatile("global_load_dword %0, %2, off sc0\n\t"
               "global_load_dword %1, %3, off sc0"
               : "=&v"(a), "=&v"(b) : "v"(p0), "v"(p1) : "memory");
}

// ---- counter barrier (per btile: 4 group counters in ONE 128B line).
// Producers (8 per group) atomicAdd their group counter (device-scope,
// baseline-proven G12). Waiters poll with 1 lane/wave (grp) or 4 lanes
// (full) — 256x fewer IF$ poll streams than the 32-flag x 32-lane scheme.
__device__ __forceinline__ void barc_arrive(unsigned* ctr, int grp, unsigned* barno){
  asm volatile("s_waitcnt vmcnt(0)" ::: "memory");  // data stores ack'd at coherence pt
  __syncthreads();
  ++(*barno);
  if (threadIdx.x == 0)
    __hip_atomic_fetch_add(&ctr[grp], 1u, __ATOMIC_RELAXED, __HIP_MEMORY_SCOPE_AGENT);
}
__device__ __forceinline__ void barc_wait_full(const unsigned* ctr, unsigned barno){
  if (threadIdx.x < 4){
    while (__hip_atomic_load(&ctr[threadIdx.x], __ATOMIC_RELAXED,
                             __HIP_MEMORY_SCOPE_AGENT) < 8u*barno) {}
  }
  __syncthreads();
}
// encoder: wave wk consumes only producer-group wk (jblk 8wk..8wk+7 = its
// K-slice). 1 poller lane per wave; wave reconvergence orders the rest.
// No __syncthreads: cross-wave LDS ordering comes from barc_arrive's sync.
__device__ __forceinline__ void barc_wait_grp(const unsigned* ctr, unsigned barno, int wk){
  if ((threadIdx.x & 63) == 0){
    while (__hip_atomic_load(&ctr[wk], __ATOMIC_RELAXED,
                             __HIP_MEMORY_SCOPE_AGENT) < 8u*barno) {}
  }
  __builtin_amdgcn_sched_barrier(0);  // keep volatile data loads behind the spin
}

// ---- pre-kernels: fp32 -> fp16 ----
__global__ __launch_bounds__(256) void cvt_plain(const float* __restrict__ s,
                                                 ushort* __restrict__ d, int n){
  for (int i = blockIdx.x*256 + threadIdx.x; i < n; i += gridDim.x*256)
    d[i] = __half_as_ushort(__float2half(s[i]));
}
// src [b][s][f] -> src16T [s][f>>3][b][f&7]
__global__ __launch_bounds__(256) void cvt_src(const float* __restrict__ s,
                                               ushort* __restrict__ d){
  for (int i = blockIdx.x*256 + threadIdx.x; i < BB*SS*FF; i += gridDim.x*256){
    int f = i & 63, st = (i >> 6) & 511, b = i >> 15;
    d[(((size_t)st*8 + (f>>3))*128 + b)*8 + (f&7)] = __half_as_ushort(__float2half(s[i]));
  }
}

// h slots (btile-major: each (parity,btile) slab = contiguous 32KB, stays in one
// XCD's L2 in LOC mode):  ushort h16[2][btile=8][o=128][b16=16][8]   (o = j>>3)
// pred: float ppsl[2][8 btile][32 jblk][16 m]
template<bool LOC>
__device__ __forceinline__ void run_loop(
  int tid, int btile, int jblk, unsigned barno,
  const float* __restrict__ tgt,
  const _Float16* __restrict__ src16T,
  const _Float16* __restrict__ dwhh16,
  const float* __restrict__ dWih,
  const float* __restrict__ dbih, const float* __restrict__ dbhh,
  const float* __restrict__ fcW, float fcb0v,
  float* __restrict__ out, ushort* __restrict__ h16u,
  float* __restrict__ ppsl, unsigned* __restrict__ ctr,
  half8 (&Bh)[64], const half8 (&Bx)[8],
  float (&ebv)[8], float (&wxv)[8], float (&fcwv)[2],
  float (&Ct4)[4][16][132], float (&xacc)[2][16], float (&predsum)[16])
{
  const int wk = tid >> 6;               // k-quarter (K=256)
  const int l  = tid & 63;
  const int la = l & 15, lq = l >> 4;    // frag: row/col-in-tile, k-octet-quarter
  const int m = tid & 15, q = tid >> 4;  // epilogue: (b=m, j-pair 2q,2q+1)
  const int grp = jblk >> 3;             // producer group (8 jblks each)
  float cc0 = 0.f, cc1 = 0.f;            // cell state in registers for all 639 steps

  for (int t = 0; t < SS + TT - 1; t++){
    const bool enc = (t < SS);
    f32x4 acc[8];
    #pragma unroll
    for (int nt = 0; nt < 8; nt++)
      #pragma unroll
      for (int r = 0; r < 4; r++) acc[nt][r] = 0.f;

    if (t == SS){   // decoder switch (in-register)
      #pragma unroll
      for (int kc = 0; kc < 8; kc++)
        #pragma unroll
        for (int nt = 0; nt < 8; nt++){
          size_t grow = (size_t)((nt>>1)*HH + jblk*32 + (nt&1)*16 + la);
          Bh[kc*8+nt] = *(const half8*)(dwhh16 + grow*HH + wk*256 + kc*32 + lq*8);
        }
      #pragma unroll
      for (int g = 0; g < 4; g++)
        #pragma unroll
        for (int u = 0; u < 2; u++){
          int jg = jblk*32 + 2*q + u;
          ebv[g*2+u] = dbih[g*HH + jg] + dbhh[g*HH + jg];
          wxv[g*2+u] = dWih[g*HH + jg];
        }
      fcwv[0] = fcW[jblk*32 + 2*q];
      fcwv[1] = fcW[jblk*32 + 2*q + 1];
    }

    // encoder x-part (waves 0,1 each K=32) before the wait
    if (enc && wk < 2){
      half8 xa = *(const half8*)(src16T +
                   (((size_t)t*8 + wk*4 + lq)*128 + btile*16 + la)*8);
      #pragma unroll
      for (int nt = 0; nt < 8; nt++)
        acc[nt] = __builtin_amdgcn_mfma_f32_16x16x32_f16(xa, Bx[nt], acc[nt], 0,0,0);
    }

    // wave-local group wait while only h is consumed; full wait once pred needed
    if (t <= SS) barc_wait_grp(ctr, barno, wk);
    else         barc_wait_full(ctr, barno);

    float pv0 = 0.f, pv1 = 0.f;
    const bool haspred = (!enc && t > SS);
    if (haspred){   // pred partial loads (latency hidden under h loads)
      const float* pp = ppsl + ((size_t)(((t+1)&1)*NBT + btile)*NJB)*16;
      if constexpr (LOC){
        ld2f_issue_sc0(pp + (size_t)q*16 + m, pp + (size_t)(q+16)*16 + m, pv0, pv1);
      } else {
        pv0 = aloadf(pp + (size_t)q*16 + m);
        pv1 = aloadf(pp + (size_t)(q+16)*16 + m);
      }
    }

    // ---- h K-loop: L2(sc0) / IF$(sc1) loads -> MFMA, no LDS, no syncs ----
    if (t > 0){
      const ushort* hb = h16u + ((size_t)((t&1)*8 + btile))*16384
                       + (size_t)wk*4096 + (size_t)lq*128 + (size_t)la*8;
      if constexpr (LOC){
        uint4v hv[8];
        asm volatile(
          "global_load_dwordx4 %0, %8, off sc0\n\t"
          "global_load_dwordx4 %1, %8, off offset:1024 sc0\n\t"
          "global_load_dwordx4 %2, %8, off offset:2048 sc0\n\t"
          "global_load_dwordx4 %3, %8, off offset:3072 sc0\n\t"
          "global_load_dwordx4 %4, %9, off sc0\n\t"
          "global_load_dwordx4 %5, %9, off offset:1024 sc0\n\t"
          "global_load_dwordx4 %6, %9, off offset:2048 sc0\n\t"
          "global_load_dwordx4 %7, %9, off offset:3072 sc0\n\t"
          "s_waitcnt vmcnt(0)"
          : "=&v"(hv[0]), "=&v"(hv[1]), "=&v"(hv[2]), "=&v"(hv[3]),
            "=&v"(hv[4]), "=&v"(hv[5]), "=&v"(hv[6]), "=&v"(hv[7])
          : "v"(hb), "v"(hb + 2048)
          : "memory");
        __builtin_amdgcn_sched_barrier(0);
        #pragma unroll
        for (int kc = 0; kc < 8; kc++){
          union { uint4v u; half8 h; } ua; ua.u = hv[kc];
          #pragma unroll
          for (int nt = 0; nt < 8; nt++)
            acc[nt] = __builtin_amdgcn_mfma_f32_16x16x32_f16(ua.h, Bh[kc*8+nt], acc[nt], 0,0,0);
        }
      } else {
        u64 w0[8], w1[8];
        #pragma unroll
        for (int kc = 0; kc < 8; kc++){
          const u64* p = (const u64*)(hb + (size_t)kc*512);
          w0[kc] = aload64(p); w1[kc] = aload64(p+1);
        }
        #pragma unroll
        for (int kc = 0; kc < 8; kc++){
          union { u64 qq[2]; half8 v; } ua;
          ua.qq[0] = w0[kc]; ua.qq[1] = w1[kc];
          #pragma unroll
          for (int nt = 0; nt < 8; nt++)
            acc[nt] = __builtin_amdgcn_mfma_f32_16x16x32_f16(ua.v, Bh[kc*8+nt], acc[nt], 0,0,0);
        }
      }
    }

    if constexpr (LOC){
      // ordering fence: pred regs valid only after the h-asm's vmcnt(0)
      if (haspred) asm volatile("" : "+v"(pv0), "+v"(pv1));
    }

    // ---- epilogue: 4-way k-reduce + gate transpose through LDS ----
    if (tid < 16) predsum[tid] = 0.f;
    if (tid >= 16 && tid < 32) xacc[(t+1)&1][tid-16] = 0.f;
    #pragma unroll
    for (int nt = 0; nt < 8; nt++)
      #pragma unroll
      for (int r = 0; r < 4; r++)
        Ct4[wk][lq*4 + r][nt*16 + la] = acc[nt][r];   // 16x16 C/D: col=la, row=lq*4+r
    float xr = 0.f;
    if (!enc){
      if (t == SS) xr = tgt[(size_t)(btile*16 + m)*TT];
      else atomicAdd(&xacc[t&1][m], pv0 + pv1);
    }
    __syncthreads();
    if (!enc && t > SS){
      xr = xacc[t&1][m] + fcb0v;
      if (jblk == 0 && tid < 16)
        out[(size_t)(btile*16 + tid)*TT + (t - SS)] = xacc[t&1][tid] + fcb0v;
    }

    float gv[8];
    #pragma unroll
    for (int g = 0; g < 4; g++)
      #pragma unroll
      for (int u = 0; u < 2; u++){
        int n = g*32 + 2*q + u;
        float s2 = ((Ct4[0][m][n] + Ct4[1][m][n]) + (Ct4[2][m][n] + Ct4[3][m][n]))
                 + ebv[g*2+u];
        if (!enc) s2 += xr * wxv[g*2+u];
        gv[g*2+u] = s2;
      }
    float h2[2];
    #pragma unroll
    for (int u = 0; u < 2; u++){
      float si = sigm(gv[0+u]), sf = sigm(gv[2+u]), so = sigm(gv[6+u]);
      float tg = tfast(gv[4+u]);
      float c = u ? cc1 : cc0;
      c = sf*c + si*tg;
      if (u) cc1 = c; else cc0 = c;
      h2[u] = so * tfast(c);
    }
    {  // h(t+1) store: packed dword (j=2q,2q+1 adjacent in 16B slot)
      int o = jblk*4 + (q >> 2);
      unsigned hvw = (unsigned)__half_as_ushort(__float2half(h2[0]))
                   | ((unsigned)__half_as_ushort(__float2half(h2[1])) << 16);
      unsigned* hp = (unsigned*)(h16u + ((size_t)(((t+1)&1)*8 + btile))*16384
                                 + ((size_t)o*16 + m)*8 + (q&3)*2);
      if constexpr (LOC) stu_sc0(hp, hvw); else astoreu(hp, hvw);
    }
    if (!enc){
      atomicAdd(&predsum[m], h2[0]*fcwv[0] + h2[1]*fcwv[1]);
      __syncthreads();
      if (tid < 16){
        float* pps = ppsl + (((size_t)(t&1)*NBT + btile)*NJB + jblk)*16 + tid;
        if constexpr (LOC) stf_sc0(pps, predsum[tid]); else astoref(pps, predsum[tid]);
      }
    }
    barc_arrive(ctr, grp, &barno);   // vmcnt-drain (L2 in LOC, IF$ in fallback)
  }

  // ---- final column 127 = fc(h(127)): pred of t=638 at parity 0 ----
  if (jblk == 0){
    barc_wait_full(ctr, barno);
    const float* pp = ppsl + ((size_t)btile*NJB)*16;
    float a, b;
    if constexpr (LOC){
      ld2f_issue_sc0(pp + (size_t)q*16 + m, pp + (size_t)(q+16)*16 + m, a, b);
      asm volatile("s_waitcnt vmcnt(0)" ::: "memory");
      asm volatile("" : "+v"(a), "+v"(b));
    } else {
      a = aloadf(pp + (size_t)q*16 + m);
      b = aloadf(pp + (size_t)(q+16)*16 + m);
    }
    atomicAdd(&xacc[1][m], a + b);        // zeroed during t=638
    __syncthreads();
    if (tid < 16)
      out[(size_t)(btile*16 + tid)*TT + (TT-1)] = xacc[1][tid] + fcb0v;
  }
}

__global__ __launch_bounds__(NTHR, 1) void seq_kernel(
  const float*  __restrict__ tgt,
  const _Float16* __restrict__ src16T,  // [512][8][128][8]
  const _Float16* __restrict__ wih16,   // [4H][64]
  const _Float16* __restrict__ ewhh16,  // [4H][1024]
  const _Float16* __restrict__ dwhh16,  // [4H][1024]
  const float* __restrict__ ebih, const float* __restrict__ ebhh,
  const float* __restrict__ dWih,
  const float* __restrict__ dbih, const float* __restrict__ dbhh,
  const float* __restrict__ fcW, const float* __restrict__ fcb,
  float* __restrict__ out, ushort* h16u, float* ppsl, unsigned* barctr,
  unsigned* xcdtab)
{
  __shared__ float Ct4[4][16][132];  // [wk][m][n], pad 132: <=2-way bank alias (free)
  __shared__ float xacc[2][16];
  __shared__ float predsum[16];
  __shared__ int s_loc;

  const int tid = threadIdx.x;
  const int wk  = tid >> 6;
  const int l   = tid & 63;
  const int la  = l & 15, lq = l >> 4;
  // co-locate each btile's 32 jblks on one XCD (bid%8 -> XCD heuristic; VERIFIED
  // below via HW_REG_XCC_ID ballot — sc0 data paths only engage if uniform)
  const int btile = blockIdx.x & 7;
  const int jblk  = blockIdx.x >> 3;
  const int q = tid >> 4;

  // ---- B fragments to registers: Bh[kc*8+nt], kc=k-chunk(32) in wave, nt=n-tile ----
  half8 Bh[64];
  #pragma unroll
  for (int kc = 0; kc < 8; kc++)
    #pragma unroll
    for (int nt = 0; nt < 8; nt++){
      size_t grow = (size_t)((nt>>1)*HH + jblk*32 + (nt&1)*16 + la);
      Bh[kc*8+nt] = *(const half8*)(ewhh16 + grow*HH + wk*256 + kc*32 + lq*8);
    }
  half8 Bx[8];
  if (wk < 2)
    #pragma unroll
    for (int nt = 0; nt < 8; nt++){
      size_t grow = (size_t)((nt>>1)*HH + jblk*32 + (nt&1)*16 + la);
      Bx[nt] = *(const half8*)(wih16 + grow*FF + wk*32 + lq*8);
    }

  float ebv[8], wxv[8], fcwv[2];
  #pragma unroll
  for (int g = 0; g < 4; g++)
    #pragma unroll
    for (int u = 0; u < 2; u++){
      int jg = jblk*32 + 2*q + u;
      ebv[g*2+u] = ebih[g*HH + jg] + ebhh[g*HH + jg];
      wxv[g*2+u] = 0.f;
    }
  fcwv[0] = fcwv[1] = 0.f;
  const float fcb0v = fcb[0];

  if (jblk == 0 && tid < 16) out[(size_t)(btile*16 + tid)*TT] = 0.f;

  // ---- publish XCC_ID, then the initial counter barrier (arrive's vmcnt(0)
  // drains the publish; full-wait -> all 32 peers' entries visible) ----
  unsigned xcc;
  asm volatile("s_getreg_b32 %0, hwreg(HW_REG_XCC_ID)" : "=s"(xcc));
  if (tid == 0) astoreu(&xcdtab[btile*NJB + jblk], xcc + 1u);

  unsigned* ctr = barctr + btile*32;   // 4 counters used; 128B line per btile
  unsigned barno = 0;
  barc_arrive(ctr, jblk >> 3, &barno);
  barc_wait_full(ctr, barno);

  if (tid < 64){
    unsigned ent = 1u;
    if (tid < NJB) ent = aloadu(&xcdtab[btile*NJB + tid]);
    unsigned ref = __shfl(ent, 0, 64);
    bool ok = (tid < NJB) ? (ent == ref && ent != 0u) : true;
    unsigned long long bal = __ballot(ok);
    if (tid == 0) s_loc = (bal == ~0ull) ? 1 : 0;
  }
  __syncthreads();

  if (s_loc)
    run_loop<true >(tid, btile, jblk, barno, tgt, src16T, dwhh16, dWih, dbih, dbhh,
                    fcW, fcb0v, out, h16u, ppsl, ctr, Bh, Bx, ebv, wxv, fcwv,
                    Ct4, xacc, predsum);
  else
    run_loop<false>(tid, btile, jblk, barno, tgt, src16T, dwhh16, dWih, dbih, dbhh,
                    fcW, fcb0v, out, h16u, ppsl, ctr, Bh, Bx, ebv, wxv, fcwv,
                    Ct4, xacc, predsum);
}

extern "C" void kernel_launch(void* const* d_in, const int* in_sizes, int n_in,
                              void* d_out, int out_size, void* d_ws, size_t ws_size,
                              hipStream_t stream){
  (void)in_sizes; (void)n_in; (void)out_size; (void)ws_size;
  const float* src  = (const float*)d_in[0];
  const float* tgt  = (const float*)d_in[1];
  const float* eWih = (const float*)d_in[2];
  const float* eWhh = (const float*)d_in[3];
  const float* ebih = (const float*)d_in[4];
  const float* ebhh = (const float*)d_in[5];
  const float* dWih = (const float*)d_in[6];
  const float* dWhh = (const float*)d_in[7];
  const float* dbih = (const float*)d_in[8];
  const float* dbhh = (const float*)d_in[9];
  const float* fcW  = (const float*)d_in[10];
  const float* fcb  = (const float*)d_in[11];
  float* out = (float*)d_out;

  // ws carve (ushort units)
  ushort* h16    = (ushort*)d_ws;          // 2*8*128*16*8     = 262144
  ushort* src16T = h16    + 262144;        // 512*8*128*8      = 4194304
  ushort* wih16  = src16T + 4194304;       // 4096*64          = 262144
  ushort* ewhh16 = wih16  + 262144;        // 4096*1024        = 4194304
  ushort* dwhh16 = ewhh16 + 4194304;       // 4096*1024        = 4194304
  float*  ppsl   = (float*)(dwhh16 + 4194304);     // 2*8*32*16 = 8192 floats
  unsigned* barctr = (unsigned*)(ppsl + 8192);     // 8 btiles x 32 u32 (128B/btile)
  unsigned* xcdtab = barctr + NBT*NJB;             // 8 x 32 u32

  hipMemsetAsync(barctr, 0, 2*NBT*NJB*sizeof(unsigned), stream);
  cvt_src  <<<4096, 256, 0, stream>>>(src, src16T);
  cvt_plain<<<1024, 256, 0, stream>>>(eWih, wih16,  4*HH*FF);
  cvt_plain<<<4096, 256, 0, stream>>>(eWhh, ewhh16, 4*HH*HH);
  cvt_plain<<<4096, 256, 0, stream>>>(dWhh, dwhh16, 4*HH*HH);
  seq_kernel<<<dim3(NBLK), dim3(NTHR), 0, stream>>>(
      tgt, (const _Float16*)src16T, (const _Float16*)wih16,
      (const _Float16*)ewhh16, (const _Float16*)dwhh16,
      ebih, ebhh, dWih, dbih, dbhh, fcW, fcb, out, h16, ppsl, barctr,
      xcdtab);
}

// Round 6
// 2456.247 us; speedup vs baseline: 1.0809x; 1.0763x over previous
//
#include <hip/hip_runtime.h>
#include <hip/hip_fp16.h>
#include <math.h>

#define BB 128
#define SS 512
#define TT 128
#define FF 64
#define HH 1024

#define NBT 8      // batch groups, M=16 each (independent barrier domains)
#define NJB 32     // j-blocks, N=128 each (4 gates x 32 j)
#define NBLK 256
#define NTHR 256   // 4 waves = 4 k-quarters (K=256), full N=128 per wave

typedef _Float16 half8 __attribute__((ext_vector_type(8)));
typedef float    f32x4 __attribute__((ext_vector_type(4)));
typedef float    f32x2 __attribute__((ext_vector_type(2)));
typedef unsigned uint4v __attribute__((ext_vector_type(4)));
typedef unsigned long long u64;

// ---- fast transcendentals (rel err ~1e-6 << fp16 noise floor) ----
__device__ __forceinline__ float rcpf(float x){ return __builtin_amdgcn_rcpf(x); }
__device__ __forceinline__ float sigm(float x){ return rcpf(1.f + __expf(-x)); }
__device__ __forceinline__ float tfast(float x){
  float a = fabsf(x);
  float e = __expf(-2.f*a);
  float t = (1.f - e) * rcpf(1.f + e);
  return copysignf(t, x);
}

// ---- agent (IF$) scope: sc1, cross-XCD coherent (baseline-proven) ----
__device__ __forceinline__ u64 aload64(const u64* p){
  return __hip_atomic_load(p, __ATOMIC_RELAXED, __HIP_MEMORY_SCOPE_AGENT);
}
__device__ __forceinline__ float aloadf(const float* p){
  return __hip_atomic_load(p, __ATOMIC_RELAXED, __HIP_MEMORY_SCOPE_AGENT);
}
__device__ __forceinline__ unsigned aloadu(const unsigned* p){
  return __hip_atomic_load(p, __ATOMIC_RELAXED, __HIP_MEMORY_SCOPE_AGENT);
}
__device__ __forceinline__ void astoref(float* p, float v){
  __hip_atomic_store(p, v, __ATOMIC_RELAXED, __HIP_MEMORY_SCOPE_AGENT);
}
__device__ __forceinline__ void astoreu(unsigned* p, unsigned v){
  __hip_atomic_store(p, v, __ATOMIC_RELAXED, __HIP_MEMORY_SCOPE_AGENT);
}

// ---- XCD-local DATA ops: sc0 = bypass L1, coherence point = per-XCD L2.
// r3 evidence: 639 steps of cross-block h deps bit-correct via sc0 ld/st.
// Used ONLY for one-shot bulk data after a proven barrier; NEVER for spins
// (sc0 spins hung in r1/r2/r4 — mechanism unknown, empirically fatal).
__device__ __forceinline__ void stu_sc0(unsigned* p, unsigned v){
  asm volatile("global_store_dword %0, %1, off sc0" :: "v"(p), "v"(v) : "memory");
}
__device__ __forceinline__ void stf_sc0(float* p, float v){
  asm volatile("global_store_dword %0, %1, off sc0" :: "v"(p), "v"(v) : "memory");
}
// issue-only (NO waitcnt): drained by a later volatile-asm vmcnt(0); outputs
// consumed only after the reuse-fence asm (guide rule #18).
__device__ __forceinline__ void ld2f_issue_sc0(const float* p0, const float* p1,
                                               float& a, float& b){
  asm volatile("global_load_dword %0, %2, off sc0\n\t"
               "global_load_dword %1, %3, off sc0"
               : "=&v"(a), "=&v"(b) : "v"(p0), "v"(p1) : "memory");
}

// ---- counter barrier (per btile: 4 group counters in ONE 128B line).
// Producers (8 per group) atomicAdd their group counter (device-scope,
// baseline-proven G12). Waiters poll with 1 lane/wave (grp) or 4 lanes (full).
__device__ __forceinline__ void barc_arrive(unsigned* ctr, int grp, unsigned* barno){
  asm volatile("s_waitcnt vmcnt(0)" ::: "memory");  // data stores ack'd at coherence pt
  __syncthreads();
  ++(*barno);
  if (threadIdx.x == 0)
    __hip_atomic_fetch_add(&ctr[grp], 1u, __ATOMIC_RELAXED, __HIP_MEMORY_SCOPE_AGENT);
}
__device__ __forceinline__ void barc_wait_full(const unsigned* ctr, unsigned barno){
  if (threadIdx.x < 4){
    while (__hip_atomic_load(&ctr[threadIdx.x], __ATOMIC_RELAXED,
                             __HIP_MEMORY_SCOPE_AGENT) < 8u*barno) {}
  }
  __syncthreads();
}
// encoder: wave wk consumes only producer-group wk (jblk 8wk..8wk+7 = its
// K-slice). 1 poller lane per wave; wave reconvergence orders the rest.
// No __syncthreads: cross-wave LDS ordering comes from barc_arrive's sync.
__device__ __forceinline__ void barc_wait_grp(const unsigned* ctr, unsigned barno, int wk){
  if ((threadIdx.x & 63) == 0){
    while (__hip_atomic_load(&ctr[wk], __ATOMIC_RELAXED,
                             __HIP_MEMORY_SCOPE_AGENT) < 8u*barno) {}
  }
  __builtin_amdgcn_sched_barrier(0);  // keep volatile data loads behind the spin
}

// ---- pre-kernels: fp32 -> fp16 ----
__global__ __launch_bounds__(256) void cvt_plain(const float* __restrict__ s,
                                                 ushort* __restrict__ d, int n){
  for (int i = blockIdx.x*256 + threadIdx.x; i < n; i += gridDim.x*256)
    d[i] = __half_as_ushort(__float2half(s[i]));
}
// src [b][s][f] -> src16T [s][f>>3][b][f&7]
__global__ __launch_bounds__(256) void cvt_src(const float* __restrict__ s,
                                               ushort* __restrict__ d){
  for (int i = blockIdx.x*256 + threadIdx.x; i < BB*SS*FF; i += gridDim.x*256){
    int f = i & 63, st = (i >> 6) & 511, b = i >> 15;
    d[(((size_t)st*8 + (f>>3))*128 + b)*8 + (f&7)] = __half_as_ushort(__float2half(s[i]));
  }
}

// h slots (btile-major: each (parity,btile) slab = contiguous 32KB, stays in one
// XCD's L2 in LOC mode):  ushort h16[2][btile=8][o=128][b16=16][8]   (o = j>>3)
// pred: float ppsl[2][8 btile][32 jblk][16 m]
template<bool LOC>
__device__ __forceinline__ void run_loop(
  int tid, int btile, int jblk, unsigned barno,
  const float* __restrict__ tgt,
  const _Float16* __restrict__ src16T,
  const _Float16* __restrict__ dwhh16,
  const float* __restrict__ dWih,
  const float* __restrict__ dbih, const float* __restrict__ dbhh,
  const float* __restrict__ fcW, float fcb0v,
  float* __restrict__ out, ushort* __restrict__ h16u,
  float* __restrict__ ppsl, unsigned* __restrict__ ctr,
  half8 (&Bh)[64], const half8 (&Bx)[8],
  float (&ebv)[8], float (&wxv)[8], float (&fcwv)[2],
  float (&Ct4)[4][16][130], float (&xacc)[2][16], float (&predsum)[16])
{
  const int wk = tid >> 6;               // k-quarter (K=256)
  const int l  = tid & 63;
  const int la = l & 15, lq = l >> 4;    // frag: row/col-in-tile, k-octet-quarter
  const int m = tid & 15, q = tid >> 4;  // epilogue: (b=m, j-pair 2q,2q+1)
  const int grp = jblk >> 3;             // producer group (8 jblks each)
  float cc0 = 0.f, cc1 = 0.f;            // cell state in registers for all 639 steps

  // x software pipeline: xa holds the src operand for the CURRENT step (wk<2),
  // loaded one step ahead so its ~700cy L3 latency hides under epilogue+arrive.
  half8 xa{};
  if (wk < 2)
    xa = *(const half8*)(src16T + (((size_t)(wk*4 + lq))*128 + btile*16 + la)*8);

  for (int t = 0; t < SS + TT - 1; t++){
    const bool enc = (t < SS);
    f32x4 acc[8];
    #pragma unroll
    for (int nt = 0; nt < 8; nt++)
      #pragma unroll
      for (int r = 0; r < 4; r++) acc[nt][r] = 0.f;

    if (t == SS){   // decoder switch (in-register)
      #pragma unroll
      for (int kc = 0; kc < 8; kc++)
        #pragma unroll
        for (int nt = 0; nt < 8; nt++){
          size_t grow = (size_t)((nt>>1)*HH + jblk*32 + (nt&1)*16 + la);
          Bh[kc*8+nt] = *(const half8*)(dwhh16 + grow*HH + wk*256 + kc*32 + lq*8);
        }
      #pragma unroll
      for (int g = 0; g < 4; g++)
        #pragma unroll
        for (int u = 0; u < 2; u++){
          int jg = jblk*32 + 2*q + u;
          ebv[g*2+u] = dbih[g*HH + jg] + dbhh[g*HH + jg];
          wxv[g*2+u] = dWih[g*HH + jg];
        }
      fcwv[0] = fcW[jblk*32 + 2*q];
      fcwv[1] = fcW[jblk*32 + 2*q + 1];
    }

    // encoder x-part (waves 0,1 each K=32) before the wait, operand prefetched
    if (enc && wk < 2){
      #pragma unroll
      for (int nt = 0; nt < 8; nt++)
        acc[nt] = __builtin_amdgcn_mfma_f32_16x16x32_f16(xa, Bx[nt], acc[nt], 0,0,0);
    }

    // wave-local group wait while only h is consumed; full wait once pred needed
    if (t <= SS) barc_wait_grp(ctr, barno, wk);
    else         barc_wait_full(ctr, barno);

    float pv0 = 0.f, pv1 = 0.f;
    const bool haspred = (!enc && t > SS);
    if (haspred){   // pred partial loads (latency hidden under h loads)
      const float* pp = ppsl + ((size_t)(((t+1)&1)*NBT + btile)*NJB)*16;
      if constexpr (LOC){
        ld2f_issue_sc0(pp + (size_t)q*16 + m, pp + (size_t)(q+16)*16 + m, pv0, pv1);
      } else {
        pv0 = aloadf(pp + (size_t)q*16 + m);
        pv1 = aloadf(pp + (size_t)(q+16)*16 + m);
      }
    }

    // ---- h K-loop: L2(sc0) / IF$(sc1) loads -> MFMA, no LDS, no syncs ----
    if (t > 0){
      const ushort* hb = h16u + ((size_t)((t&1)*8 + btile))*16384
                       + (size_t)wk*4096 + (size_t)lq*128 + (size_t)la*8;
      if constexpr (LOC){
        uint4v hv[8];
        asm volatile(
          "global_load_dwordx4 %0, %8, off sc0\n\t"
          "global_load_dwordx4 %1, %8, off offset:1024 sc0\n\t"
          "global_load_dwordx4 %2, %8, off offset:2048 sc0\n\t"
          "global_load_dwordx4 %3, %8, off offset:3072 sc0\n\t"
          "global_load_dwordx4 %4, %9, off sc0\n\t"
          "global_load_dwordx4 %5, %9, off offset:1024 sc0\n\t"
          "global_load_dwordx4 %6, %9, off offset:2048 sc0\n\t"
          "global_load_dwordx4 %7, %9, off offset:3072 sc0\n\t"
          "s_waitcnt vmcnt(0)"
          : "=&v"(hv[0]), "=&v"(hv[1]), "=&v"(hv[2]), "=&v"(hv[3]),
            "=&v"(hv[4]), "=&v"(hv[5]), "=&v"(hv[6]), "=&v"(hv[7])
          : "v"(hb), "v"(hb + 2048)
          : "memory");
        __builtin_amdgcn_sched_barrier(0);
        #pragma unroll
        for (int kc = 0; kc < 8; kc++){
          union { uint4v u; half8 h; } ua; ua.u = hv[kc];
          #pragma unroll
          for (int nt = 0; nt < 8; nt++)
            acc[nt] = __builtin_amdgcn_mfma_f32_16x16x32_f16(ua.h, Bh[kc*8+nt], acc[nt], 0,0,0);
        }
      } else {
        u64 w0[8], w1[8];
        #pragma unroll
        for (int kc = 0; kc < 8; kc++){
          const u64* p = (const u64*)(hb + (size_t)kc*512);
          w0[kc] = aload64(p); w1[kc] = aload64(p+1);
        }
        #pragma unroll
        for (int kc = 0; kc < 8; kc++){
          union { u64 qq[2]; half8 v; } ua;
          ua.qq[0] = w0[kc]; ua.qq[1] = w1[kc];
          #pragma unroll
          for (int nt = 0; nt < 8; nt++)
            acc[nt] = __builtin_amdgcn_mfma_f32_16x16x32_f16(ua.v, Bh[kc*8+nt], acc[nt], 0,0,0);
        }
      }
    }

    if constexpr (LOC){
      // ordering fence: pred regs valid only after the h-asm's vmcnt(0)
      if (haspred) asm volatile("" : "+v"(pv0), "+v"(pv1));
    }

    // prefetch x for step t+1 (issue-only; consumed before the next wait).
    if (t + 1 < SS && wk < 2)
      xa = *(const half8*)(src16T + (((size_t)(t+1)*8 + wk*4 + lq)*128 + btile*16 + la)*8);

    // ---- epilogue: 4-way k-reduce + gate transpose through LDS ----
    if (tid < 16) predsum[tid] = 0.f;
    if (tid >= 16 && tid < 32) xacc[(t+1)&1][tid-16] = 0.f;
    #pragma unroll
    for (int nt = 0; nt < 8; nt++)
      #pragma unroll
      for (int r = 0; r < 4; r++)
        Ct4[wk][lq*4 + r][nt*16 + la] = acc[nt][r];   // 16x16 C/D: col=la, row=lq*4+r
    float xr = 0.f;
    if (!enc){
      if (t == SS) xr = tgt[(size_t)(btile*16 + m)*TT];
      else atomicAdd(&xacc[t&1][m], pv0 + pv1);
    }
    __syncthreads();
    if (!enc && t > SS){
      xr = xacc[t&1][m] + fcb0v;
      if (jblk == 0 && tid < 16)
        out[(size_t)(btile*16 + tid)*TT + (t - SS)] = xacc[t&1][tid] + fcb0v;
    }

    float gv[8];
    {   // paired b64 reads: float idx m*130 + g*32 + 2q -> float2 idx m*65+g*16+q
      const f32x2* C2 = (const f32x2*)(&Ct4[0][0][0]);
      const int base = m*65 + q;
      #pragma unroll
      for (int g = 0; g < 4; g++){
        f32x2 a0 = C2[           base + g*16];
        f32x2 a1 = C2[1040     + base + g*16];
        f32x2 a2 = C2[2080     + base + g*16];
        f32x2 a3 = C2[3120     + base + g*16];
        float sx = ((a0[0] + a1[0]) + (a2[0] + a3[0])) + ebv[g*2+0];
        float sy = ((a0[1] + a1[1]) + (a2[1] + a3[1])) + ebv[g*2+1];
        if (!enc){ sx += xr * wxv[g*2+0]; sy += xr * wxv[g*2+1]; }
        gv[g*2+0] = sx; gv[g*2+1] = sy;
      }
    }
    float h2[2];
    #pragma unroll
    for (int u = 0; u < 2; u++){
      float si = sigm(gv[0+u]), sf = sigm(gv[2+u]), so = sigm(gv[6+u]);
      float tg = tfast(gv[4+u]);
      float c = u ? cc1 : cc0;
      c = sf*c + si*tg;
      if (u) cc1 = c; else cc0 = c;
      h2[u] = so * tfast(c);
    }
    {  // h(t+1) store: packed dword (j=2q,2q+1 adjacent in 16B slot)
      int o = jblk*4 + (q >> 2);
      unsigned hvw = (unsigned)__half_as_ushort(__float2half(h2[0]))
                   | ((unsigned)__half_as_ushort(__float2half(h2[1])) << 16);
      unsigned* hp = (unsigned*)(h16u + ((size_t)(((t+1)&1)*8 + btile))*16384
                                 + ((size_t)o*16 + m)*8 + (q&3)*2);
      if constexpr (LOC) stu_sc0(hp, hvw); else astoreu(hp, hvw);
    }
    if (!enc){
      atomicAdd(&predsum[m], h2[0]*fcwv[0] + h2[1]*fcwv[1]);
      __syncthreads();
      if (tid < 16){
        float* pps = ppsl + (((size_t)(t&1)*NBT + btile)*NJB + jblk)*16 + tid;
        if constexpr (LOC) stf_sc0(pps, predsum[tid]); else astoref(pps, predsum[tid]);
      }
    }
    barc_arrive(ctr, grp, &barno);   // vmcnt-drain (L2 in LOC, IF$ in fallback)
  }

  // ---- final column 127 = fc(h(127)): pred of t=638 at parity 0 ----
  if (jblk == 0){
    barc_wait_full(ctr, barno);
    const float* pp = ppsl + ((size_t)btile*NJB)*16;
    float a, b;
    if constexpr (LOC){
      ld2f_issue_sc0(pp + (size_t)q*16 + m, pp + (size_t)(q+16)*16 + m, a, b);
      asm volatile("s_waitcnt vmcnt(0)" ::: "memory");
      asm volatile("" : "+v"(a), "+v"(b));
    } else {
      a = aloadf(pp + (size_t)q*16 + m);
      b = aloadf(pp + (size_t)(q+16)*16 + m);
    }
    atomicAdd(&xacc[1][m], a + b);        // zeroed during t=638
    __syncthreads();
    if (tid < 16)
      out[(size_t)(btile*16 + tid)*TT + (TT-1)] = xacc[1][tid] + fcb0v;
  }
}

__global__ __launch_bounds__(NTHR, 1) void seq_kernel(
  const float*  __restrict__ tgt,
  const _Float16* __restrict__ src16T,  // [512][8][128][8]
  const _Float16* __restrict__ wih16,   // [4H][64]
  const _Float16* __restrict__ ewhh16,  // [4H][1024]
  const _Float16* __restrict__ dwhh16,  // [4H][1024]
  const float* __restrict__ ebih, const float* __restrict__ ebhh,
  const float* __restrict__ dWih,
  const float* __restrict__ dbih, const float* __restrict__ dbhh,
  const float* __restrict__ fcW, const float* __restrict__ fcb,
  float* __restrict__ out, ushort* h16u, float* ppsl, unsigned* barctr,
  unsigned* xcdtab)
{
  __shared__ float Ct4[4][16][130];  // [wk][m][n], stride 130: <=2-way banks (free)
  __shared__ float xacc[2][16];
  __shared__ float predsum[16];
  __shared__ int s_loc;

  const int tid = threadIdx.x;
  const int wk  = tid >> 6;
  const int l   = tid & 63;
  const int la  = l & 15, lq = l >> 4;
  // co-locate each btile's 32 jblks on one XCD (bid%8 -> XCD heuristic; VERIFIED
  // below via HW_REG_XCC_ID ballot — sc0 data paths only engage if uniform)
  const int btile = blockIdx.x & 7;
  const int jblk  = blockIdx.x >> 3;
  const int q = tid >> 4;

  // ---- B fragments to registers: Bh[kc*8+nt], kc=k-chunk(32) in wave, nt=n-tile ----
  half8 Bh[64];
  #pragma unroll
  for (int kc = 0; kc < 8; kc++)
    #pragma unroll
    for (int nt = 0; nt < 8; nt++){
      size_t grow = (size_t)((nt>>1)*HH + jblk*32 + (nt&1)*16 + la);
      Bh[kc*8+nt] = *(const half8*)(ewhh16 + grow*HH + wk*256 + kc*32 + lq*8);
    }
  half8 Bx[8];
  if (wk < 2)
    #pragma unroll
    for (int nt = 0; nt < 8; nt++){
      size_t grow = (size_t)((nt>>1)*HH + jblk*32 + (nt&1)*16 + la);
      Bx[nt] = *(const half8*)(wih16 + grow*FF + wk*32 + lq*8);
    }

  float ebv[8], wxv[8], fcwv[2];
  #pragma unroll
  for (int g = 0; g < 4; g++)
    #pragma unroll
    for (int u = 0; u < 2; u++){
      int jg = jblk*32 + 2*q + u;
      ebv[g*2+u] = ebih[g*HH + jg] + ebhh[g*HH + jg];
      wxv[g*2+u] = 0.f;
    }
  fcwv[0] = fcwv[1] = 0.f;
  const float fcb0v = fcb[0];

  if (jblk == 0 && tid < 16) out[(size_t)(btile*16 + tid)*TT] = 0.f;

  // ---- publish XCC_ID, then the initial counter barrier (arrive's vmcnt(0)
  // drains the publish; full-wait -> all 32 peers' entries visible) ----
  unsigned xcc;
  asm volatile("s_getreg_b32 %0, hwreg(HW_REG_XCC_ID)" : "=s"(xcc));
  if (tid == 0) astoreu(&xcdtab[btile*NJB + jblk], xcc + 1u);

  unsigned* ctr = barctr + btile*32;   // 4 counters used; 128B line per btile
  unsigned barno = 0;
  barc_arrive(ctr, jblk >> 3, &barno);
  barc_wait_full(ctr, barno);

  if (tid < 64){
    unsigned ent = 1u;
    if (tid < NJB) ent = aloadu(&xcdtab[btile*NJB + tid]);
    unsigned ref = __shfl(ent, 0, 64);
    bool ok = (tid < NJB) ? (ent == ref && ent != 0u) : true;
    unsigned long long bal = __ballot(ok);
    if (tid == 0) s_loc = (bal == ~0ull) ? 1 : 0;
  }
  __syncthreads();

  if (s_loc)
    run_loop<true >(tid, btile, jblk, barno, tgt, src16T, dwhh16, dWih, dbih, dbhh,
                    fcW, fcb0v, out, h16u, ppsl, ctr, Bh, Bx, ebv, wxv, fcwv,
                    Ct4, xacc, predsum);
  else
    run_loop<false>(tid, btile, jblk, barno, tgt, src16T, dwhh16, dWih, dbih, dbhh,
                    fcW, fcb0v, out, h16u, ppsl, ctr, Bh, Bx, ebv, wxv, fcwv,
                    Ct4, xacc, predsum);
}

extern "C" void kernel_launch(void* const* d_in, const int* in_sizes, int n_in,
                              void* d_out, int out_size, void* d_ws, size_t ws_size,
                              hipStream_t stream){
  (void)in_sizes; (void)n_in; (void)out_size; (void)ws_size;
  const float* src  = (const float*)d_in[0];
  const float* tgt  = (const float*)d_in[1];
  const float* eWih = (const float*)d_in[2];
  const float* eWhh = (const float*)d_in[3];
  const float* ebih = (const float*)d_in[4];
  const float* ebhh = (const float*)d_in[5];
  const float* dWih = (const float*)d_in[6];
  const float* dWhh = (const float*)d_in[7];
  const float* dbih = (const float*)d_in[8];
  const float* dbhh = (const float*)d_in[9];
  const float* fcW  = (const float*)d_in[10];
  const float* fcb  = (const float*)d_in[11];
  float* out = (float*)d_out;

  // ws carve (ushort units)
  ushort* h16    = (ushort*)d_ws;          // 2*8*128*16*8     = 262144
  ushort* src16T = h16    + 262144;        // 512*8*128*8      = 4194304
  ushort* wih16  = src16T + 4194304;       // 4096*64          = 262144
  ushort* ewhh16 = wih16  + 262144;        // 4096*1024        = 4194304
  ushort* dwhh16 = ewhh16 + 4194304;       // 4096*1024        = 4194304
  float*  ppsl   = (float*)(dwhh16 + 4194304);     // 2*8*32*16 = 8192 floats
  unsigned* barctr = (unsigned*)(ppsl + 8192);     // 8 btiles x 32 u32 (128B/btile)
  unsigned* xcdtab = barctr + NBT*NJB;             // 8 x 32 u32

  hipMemsetAsync(barctr, 0, 2*NBT*NJB*sizeof(unsigned), stream);
  cvt_src  <<<4096, 256, 0, stream>>>(src, src16T);
  cvt_plain<<<1024, 256, 0, stream>>>(eWih, wih16,  4*HH*FF);
  cvt_plain<<<4096, 256, 0, stream>>>(eWhh, ewhh16, 4*HH*HH);
  cvt_plain<<<4096, 256, 0, stream>>>(dWhh, dwhh16, 4*HH*HH);
  seq_kernel<<<dim3(NBLK), dim3(NTHR), 0, stream>>>(
      tgt, (const _Float16*)src16T, (const _Float16*)wih16,
      (const _Float16*)ewhh16, (const _Float16*)dwhh16,
      ebih, ebhh, dWih, dbih, dbhh, fcW, fcb, out, h16, ppsl, barctr,
      xcdtab);
}

// Round 7
// 2394.606 us; speedup vs baseline: 1.1087x; 1.0257x over previous
//
#include <hip/hip_runtime.h>
#include <hip/hip_fp16.h>
#include <math.h>

#define BB 128
#define SS 512
#define TT 128
#define FF 64
#define HH 1024

#define NBT 8      // batch groups, M=16 each (independent barrier domains)
#define NJB 32     // j-blocks, N=128 each (4 gates x 32 j)
#define NBLK 256
#define NTHR 256   // 4 waves = 4 k-quarters (K=256), full N=128 per wave

typedef _Float16 half8 __attribute__((ext_vector_type(8)));
typedef float    f32x4 __attribute__((ext_vector_type(4)));
typedef float    f32x2 __attribute__((ext_vector_type(2)));
typedef unsigned uint4v __attribute__((ext_vector_type(4)));
typedef unsigned long long u64;

// ---- fast transcendentals (rel err ~1e-6 << fp16 noise floor) ----
__device__ __forceinline__ float rcpf(float x){ return __builtin_amdgcn_rcpf(x); }
__device__ __forceinline__ float sigm(float x){ return rcpf(1.f + __expf(-x)); }
__device__ __forceinline__ float tfast(float x){
  float a = fabsf(x);
  float e = __expf(-2.f*a);
  float t = (1.f - e) * rcpf(1.f + e);
  return copysignf(t, x);
}

// ---- agent (IF$) scope: sc1, cross-XCD coherent (baseline-proven) ----
__device__ __forceinline__ u64 aload64(const u64* p){
  return __hip_atomic_load(p, __ATOMIC_RELAXED, __HIP_MEMORY_SCOPE_AGENT);
}
__device__ __forceinline__ float aloadf(const float* p){
  return __hip_atomic_load(p, __ATOMIC_RELAXED, __HIP_MEMORY_SCOPE_AGENT);
}
__device__ __forceinline__ unsigned aloadu(const unsigned* p){
  return __hip_atomic_load(p, __ATOMIC_RELAXED, __HIP_MEMORY_SCOPE_AGENT);
}
__device__ __forceinline__ void astoref(float* p, float v){
  __hip_atomic_store(p, v, __ATOMIC_RELAXED, __HIP_MEMORY_SCOPE_AGENT);
}
__device__ __forceinline__ void astoreu(unsigned* p, unsigned v){
  __hip_atomic_store(p, v, __ATOMIC_RELAXED, __HIP_MEMORY_SCOPE_AGENT);
}

// ---- XCD-local DATA ops: sc0 = bypass L1, coherence point = per-XCD L2.
// r3 evidence: 639 steps of cross-block h deps bit-correct via sc0 ld/st.
// Used ONLY for one-shot bulk data after a proven barrier; NEVER for spins
// (sc0 spins hung in r1/r2/r4 — mechanism unknown, empirically fatal).
__device__ __forceinline__ void stu_sc0(unsigned* p, unsigned v){
  asm volatile("global_store_dword %0, %1, off sc0" :: "v"(p), "v"(v) : "memory");
}
__device__ __forceinline__ void stf_sc0(float* p, float v){
  asm volatile("global_store_dword %0, %1, off sc0" :: "v"(p), "v"(v) : "memory");
}
// issue-only (NO waitcnt): drained by a later volatile-asm vmcnt(0); outputs
// consumed only after the reuse-fence asm (guide rule #18).
__device__ __forceinline__ void ld2f_issue_sc0(const float* p0, const float* p1,
                                               float& a, float& b){
  asm volatile("global_load_dword %0, %2, off sc0\n\t"
               "global_load_dword %1, %3, off sc0"
               : "=&v"(a), "=&v"(b) : "v"(p0), "v"(p1) : "memory");
}

// ---- counter barrier (per btile: 4 group counters in ONE 128B line).
// Producers (8 per group) atomicAdd their group counter (device-scope, proven).
// NEW (r7): arrive also issues a one-shot agent SNAPSHOT (dwordx4) of all 4
// counters. At the wait, if min(snapshot) >= target the poll is SKIPPED —
// the straggler (critical-path block) took its snapshot last, sees everyone,
// and pays ZERO detect RT. Stale-low snapshot -> harmless poll fallback.
__device__ __forceinline__ void barc_arrive(unsigned* ctr, int grp, unsigned* barno,
                                            uint4v& snap){
  asm volatile("s_waitcnt vmcnt(0)" ::: "memory");  // data stores ack'd at coherence pt
  __syncthreads();
  ++(*barno);
  if (threadIdx.x == 0){
    __hip_atomic_fetch_add(&ctr[grp], 1u, __ATOMIC_RELAXED, __HIP_MEMORY_SCOPE_AGENT);
    asm volatile("global_load_dwordx4 %0, %1, off sc0 sc1"   // agent-visibility load
                 : "=&v"(snap) : "v"(ctr) : "memory");
  }
}
// full: all 4 groups must reach 8*barno (decoder/pred + prologue/tail).
// grp : wave wk needs only producer-group wk (its K-slice), encoder path.
__device__ __forceinline__ void barc_wait(const unsigned* ctr, unsigned barno, int wk,
                                          bool full, uint4v& snap, int* s_pass){
  if (threadIdx.x == 0){
    asm volatile("s_waitcnt vmcnt(0)" ::: "memory");  // snapshot (and own pending) done
    asm volatile("" : "+v"(snap));                     // reuse-fence (rule #18)
    unsigned c01 = snap[0] < snap[1] ? snap[0] : snap[1];
    unsigned c23 = snap[2] < snap[3] ? snap[2] : snap[3];
    unsigned mn  = c01 < c23 ? c01 : c23;
    *s_pass = (mn >= 8u*barno) ? 1 : 0;
  }
  __syncthreads();
  if (!*s_pass){
    if (full){
      if (threadIdx.x < 4){
        while (__hip_atomic_load(&ctr[threadIdx.x], __ATOMIC_RELAXED,
                                 __HIP_MEMORY_SCOPE_AGENT) < 8u*barno) {}
      }
      __syncthreads();
    } else {
      if ((threadIdx.x & 63) == 0){
        while (__hip_atomic_load(&ctr[wk], __ATOMIC_RELAXED,
                                 __HIP_MEMORY_SCOPE_AGENT) < 8u*barno) {}
      }
    }
  }
  __builtin_amdgcn_sched_barrier(0);  // keep volatile data loads behind the wait
}

// ---- pre-kernels: fp32 -> fp16 ----
__global__ __launch_bounds__(256) void cvt_plain(const float* __restrict__ s,
                                                 ushort* __restrict__ d, int n){
  for (int i = blockIdx.x*256 + threadIdx.x; i < n; i += gridDim.x*256)
    d[i] = __half_as_ushort(__float2half(s[i]));
}
// src [b][s][f] -> src16T [s][f>>3][b][f&7]
__global__ __launch_bounds__(256) void cvt_src(const float* __restrict__ s,
                                               ushort* __restrict__ d){
  for (int i = blockIdx.x*256 + threadIdx.x; i < BB*SS*FF; i += gridDim.x*256){
    int f = i & 63, st = (i >> 6) & 511, b = i >> 15;
    d[(((size_t)st*8 + (f>>3))*128 + b)*8 + (f&7)] = __half_as_ushort(__float2half(s[i]));
  }
}

// h slots (btile-major: each (parity,btile) slab = contiguous 32KB, stays in one
// XCD's L2 in LOC mode):  ushort h16[2][btile=8][o=128][b16=16][8]   (o = j>>3)
// pred: float ppsl[2][8 btile][32 jblk][16 m]
template<bool LOC>
__device__ __forceinline__ void run_loop(
  int tid, int btile, int jblk, unsigned barno,
  const float* __restrict__ tgt,
  const _Float16* __restrict__ src16T,
  const _Float16* __restrict__ dwhh16,
  const float* __restrict__ dWih,
  const float* __restrict__ dbih, const float* __restrict__ dbhh,
  const float* __restrict__ fcW, float fcb0v,
  float* __restrict__ out, ushort* __restrict__ h16u,
  float* __restrict__ ppsl, unsigned* __restrict__ ctr,
  half8 (&Bh)[64], const half8 (&Bx)[8],
  float (&ebv)[8], float (&wxv)[8], float (&fcwv)[2],
  float (&Ct4)[4][16][130], float (&xacc)[2][16], float (&predsum)[16],
  uint4v& snap, int* s_pass)
{
  const int wk = tid >> 6;               // k-quarter (K=256)
  const int l  = tid & 63;
  const int la = l & 15, lq = l >> 4;    // frag: row/col-in-tile, k-octet-quarter
  const int m = tid & 15, q = tid >> 4;  // epilogue: (b=m, j-pair 2q,2q+1)
  const int grp = jblk >> 3;             // producer group (8 jblks each)
  float cc0 = 0.f, cc1 = 0.f;            // cell state in registers for all 639 steps

  // x software pipeline: xa holds the src operand for the CURRENT step (wk<2),
  // loaded one step ahead so its ~900cy L3 latency hides under epilogue+arrive.
  half8 xa{};
  if (wk < 2)
    xa = *(const half8*)(src16T + (((size_t)(wk*4 + lq))*128 + btile*16 + la)*8);

  for (int t = 0; t < SS + TT - 1; t++){
    const bool enc = (t < SS);
    f32x4 acc[8];
    #pragma unroll
    for (int nt = 0; nt < 8; nt++)
      #pragma unroll
      for (int r = 0; r < 4; r++) acc[nt][r] = 0.f;

    if (t == SS){   // decoder switch (in-register)
      #pragma unroll
      for (int kc = 0; kc < 8; kc++)
        #pragma unroll
        for (int nt = 0; nt < 8; nt++){
          size_t grow = (size_t)((nt>>1)*HH + jblk*32 + (nt&1)*16 + la);
          Bh[kc*8+nt] = *(const half8*)(dwhh16 + grow*HH + wk*256 + kc*32 + lq*8);
        }
      #pragma unroll
      for (int g = 0; g < 4; g++)
        #pragma unroll
        for (int u = 0; u < 2; u++){
          int jg = jblk*32 + 2*q + u;
          ebv[g*2+u] = dbih[g*HH + jg] + dbhh[g*HH + jg];
          wxv[g*2+u] = dWih[g*HH + jg];
        }
      fcwv[0] = fcW[jblk*32 + 2*q];
      fcwv[1] = fcW[jblk*32 + 2*q + 1];
    }

    // encoder x-part (waves 0,1 each K=32) before the wait, operand prefetched
    if (enc && wk < 2){
      #pragma unroll
      for (int nt = 0; nt < 8; nt++)
        acc[nt] = __builtin_amdgcn_mfma_f32_16x16x32_f16(xa, Bx[nt], acc[nt], 0,0,0);
    }

    // snapshot-checked wait: grp while only h consumed, full once pred needed
    barc_wait(ctr, barno, wk, /*full=*/(t > SS), snap, s_pass);

    float pv0 = 0.f, pv1 = 0.f;
    const bool haspred = (!enc && t > SS);
    if (haspred){   // pred partial loads (latency hidden under h loads)
      const float* pp = ppsl + ((size_t)(((t+1)&1)*NBT + btile)*NJB)*16;
      if constexpr (LOC){
        ld2f_issue_sc0(pp + (size_t)q*16 + m, pp + (size_t)(q+16)*16 + m, pv0, pv1);
      } else {
        pv0 = aloadf(pp + (size_t)q*16 + m);
        pv1 = aloadf(pp + (size_t)(q+16)*16 + m);
      }
    }

    // ---- h K-loop: L2(sc0) / IF$(sc1) loads -> MFMA, no LDS, no syncs ----
    if (t > 0){
      const ushort* hb = h16u + ((size_t)((t&1)*8 + btile))*16384
                       + (size_t)wk*4096 + (size_t)lq*128 + (size_t)la*8;
      if constexpr (LOC){
        uint4v hv[8];
        asm volatile(
          "global_load_dwordx4 %0, %8, off sc0\n\t"
          "global_load_dwordx4 %1, %8, off offset:1024 sc0\n\t"
          "global_load_dwordx4 %2, %8, off offset:2048 sc0\n\t"
          "global_load_dwordx4 %3, %8, off offset:3072 sc0\n\t"
          "global_load_dwordx4 %4, %9, off sc0\n\t"
          "global_load_dwordx4 %5, %9, off offset:1024 sc0\n\t"
          "global_load_dwordx4 %6, %9, off offset:2048 sc0\n\t"
          "global_load_dwordx4 %7, %9, off offset:3072 sc0\n\t"
          "s_waitcnt vmcnt(4)"            // h0..3 (and pred) done; h4..7 in flight
          : "=&v"(hv[0]), "=&v"(hv[1]), "=&v"(hv[2]), "=&v"(hv[3]),
            "=&v"(hv[4]), "=&v"(hv[5]), "=&v"(hv[6]), "=&v"(hv[7])
          : "v"(hb), "v"(hb + 2048)
          : "memory");
        __builtin_amdgcn_sched_barrier(0);
        #pragma unroll
        for (int kc = 0; kc < 4; kc++){
          union { uint4v u; half8 h; } ua; ua.u = hv[kc];
          #pragma unroll
          for (int nt = 0; nt < 8; nt++)
            acc[nt] = __builtin_amdgcn_mfma_f32_16x16x32_f16(ua.h, Bh[kc*8+nt], acc[nt], 0,0,0);
        }
        asm volatile("s_waitcnt vmcnt(0)" ::: "memory");
        __builtin_amdgcn_sched_barrier(0);
        #pragma unroll
        for (int kc = 4; kc < 8; kc++){
          union { uint4v u; half8 h; } ua; ua.u = hv[kc];
          #pragma unroll
          for (int nt = 0; nt < 8; nt++)
            acc[nt] = __builtin_amdgcn_mfma_f32_16x16x32_f16(ua.h, Bh[kc*8+nt], acc[nt], 0,0,0);
        }
      } else {
        u64 w0[8], w1[8];
        #pragma unroll
        for (int kc = 0; kc < 8; kc++){
          const u64* p = (const u64*)(hb + (size_t)kc*512);
          w0[kc] = aload64(p); w1[kc] = aload64(p+1);
        }
        #pragma unroll
        for (int kc = 0; kc < 8; kc++){
          union { u64 qq[2]; half8 v; } ua;
          ua.qq[0] = w0[kc]; ua.qq[1] = w1[kc];
          #pragma unroll
          for (int nt = 0; nt < 8; nt++)
            acc[nt] = __builtin_amdgcn_mfma_f32_16x16x32_f16(ua.v, Bh[kc*8+nt], acc[nt], 0,0,0);
        }
      }
    }

    if constexpr (LOC){
      // ordering fence: pred regs valid only after the h-asm's vmcnt(0)
      if (haspred) asm volatile("" : "+v"(pv0), "+v"(pv1));
    }

    // prefetch x for step t+1 (issue-only; consumed before the next wait).
    if (t + 1 < SS && wk < 2)
      xa = *(const half8*)(src16T + (((size_t)(t+1)*8 + wk*4 + lq)*128 + btile*16 + la)*8);

    // ---- epilogue: 4-way k-reduce + gate transpose through LDS ----
    if (tid < 16) predsum[tid] = 0.f;
    if (tid >= 16 && tid < 32) xacc[(t+1)&1][tid-16] = 0.f;
    #pragma unroll
    for (int nt = 0; nt < 8; nt++)
      #pragma unroll
      for (int r = 0; r < 4; r++)
        Ct4[wk][lq*4 + r][nt*16 + la] = acc[nt][r];   // 16x16 C/D: col=la, row=lq*4+r
    float xr = 0.f;
    if (!enc){
      if (t == SS) xr = tgt[(size_t)(btile*16 + m)*TT];
      else atomicAdd(&xacc[t&1][m], pv0 + pv1);
    }
    __syncthreads();
    if (!enc && t > SS){
      xr = xacc[t&1][m] + fcb0v;
      if (jblk == 0 && tid < 16)
        out[(size_t)(btile*16 + tid)*TT + (t - SS)] = xacc[t&1][tid] + fcb0v;
    }

    float gv[8];
    {   // paired b64 reads: float idx m*130 + g*32 + 2q -> float2 idx m*65+g*16+q
      const f32x2* C2 = (const f32x2*)(&Ct4[0][0][0]);
      const int base = m*65 + q;
      #pragma unroll
      for (int g = 0; g < 4; g++){
        f32x2 a0 = C2[           base + g*16];
        f32x2 a1 = C2[1040     + base + g*16];
        f32x2 a2 = C2[2080     + base + g*16];
        f32x2 a3 = C2[3120     + base + g*16];
        float sx = ((a0[0] + a1[0]) + (a2[0] + a3[0])) + ebv[g*2+0];
        float sy = ((a0[1] + a1[1]) + (a2[1] + a3[1])) + ebv[g*2+1];
        if (!enc){ sx += xr * wxv[g*2+0]; sy += xr * wxv[g*2+1]; }
        gv[g*2+0] = sx; gv[g*2+1] = sy;
      }
    }
    float h2[2];
    #pragma unroll
    for (int u = 0; u < 2; u++){
      float si = sigm(gv[0+u]), sf = sigm(gv[2+u]), so = sigm(gv[6+u]);
      float tg = tfast(gv[4+u]);
      float c = u ? cc1 : cc0;
      c = sf*c + si*tg;
      if (u) cc1 = c; else cc0 = c;
      h2[u] = so * tfast(c);
    }
    {  // h(t+1) store: packed dword (j=2q,2q+1 adjacent in 16B slot)
      int o = jblk*4 + (q >> 2);
      unsigned hvw = (unsigned)__half_as_ushort(__float2half(h2[0]))
                   | ((unsigned)__half_as_ushort(__float2half(h2[1])) << 16);
      unsigned* hp = (unsigned*)(h16u + ((size_t)(((t+1)&1)*8 + btile))*16384
                                 + ((size_t)o*16 + m)*8 + (q&3)*2);
      if constexpr (LOC) stu_sc0(hp, hvw); else astoreu(hp, hvw);
    }
    if (!enc){
      atomicAdd(&predsum[m], h2[0]*fcwv[0] + h2[1]*fcwv[1]);
      __syncthreads();
      if (tid < 16){
        float* pps = ppsl + (((size_t)(t&1)*NBT + btile)*NJB + jblk)*16 + tid;
        if constexpr (LOC) stf_sc0(pps, predsum[tid]); else astoref(pps, predsum[tid]);
      }
    }
    barc_arrive(ctr, grp, &barno, snap);   // vmcnt-drain + atomic + snapshot
  }

  // ---- final column 127 = fc(h(127)): pred of t=638 at parity 0 ----
  if (jblk == 0){
    barc_wait(ctr, barno, 0, /*full=*/true, snap, s_pass);
    const float* pp = ppsl + ((size_t)btile*NJB)*16;
    float a, b;
    if constexpr (LOC){
      ld2f_issue_sc0(pp + (size_t)q*16 + m, pp + (size_t)(q+16)*16 + m, a, b);
      asm volatile("s_waitcnt vmcnt(0)" ::: "memory");
      asm volatile("" : "+v"(a), "+v"(b));
    } else {
      a = aloadf(pp + (size_t)q*16 + m);
      b = aloadf(pp + (size_t)(q+16)*16 + m);
    }
    atomicAdd(&xacc[1][m], a + b);        // zeroed during t=638
    __syncthreads();
    if (tid < 16)
      out[(size_t)(btile*16 + tid)*TT + (TT-1)] = xacc[1][tid] + fcb0v;
  }
}

__global__ __launch_bounds__(NTHR, 1) void seq_kernel(
  const float*  __restrict__ tgt,
  const _Float16* __restrict__ src16T,  // [512][8][128][8]
  const _Float16* __restrict__ wih16,   // [4H][64]
  const _Float16* __restrict__ ewhh16,  // [4H][1024]
  const _Float16* __restrict__ dwhh16,  // [4H][1024]
  const float* __restrict__ ebih, const float* __restrict__ ebhh,
  const float* __restrict__ dWih,
  const float* __restrict__ dbih, const float* __restrict__ dbhh,
  const float* __restrict__ fcW, const float* __restrict__ fcb,
  float* __restrict__ out, ushort* h16u, float* ppsl, unsigned* barctr,
  unsigned* xcdtab)
{
  __shared__ float Ct4[4][16][130];  // [wk][m][n], stride 130
  __shared__ float xacc[2][16];
  __shared__ float predsum[16];
  __shared__ int s_loc;
  __shared__ int s_pass;

  const int tid = threadIdx.x;
  const int wk  = tid >> 6;
  const int l   = tid & 63;
  const int la  = l & 15, lq = l >> 4;
  // co-locate each btile's 32 jblks on one XCD (bid%8 -> XCD heuristic; VERIFIED
  // below via HW_REG_XCC_ID ballot — sc0 data paths only engage if uniform)
  const int btile = blockIdx.x & 7;
  const int jblk  = blockIdx.x >> 3;
  const int q = tid >> 4;

  // ---- B fragments to registers: Bh[kc*8+nt], kc=k-chunk(32) in wave, nt=n-tile ----
  half8 Bh[64];
  #pragma unroll
  for (int kc = 0; kc < 8; kc++)
    #pragma unroll
    for (int nt = 0; nt < 8; nt++){
      size_t grow = (size_t)((nt>>1)*HH + jblk*32 + (nt&1)*16 + la);
      Bh[kc*8+nt] = *(const half8*)(ewhh16 + grow*HH + wk*256 + kc*32 + lq*8);
    }
  half8 Bx[8];
  if (wk < 2)
    #pragma unroll
    for (int nt = 0; nt < 8; nt++){
      size_t grow = (size_t)((nt>>1)*HH + jblk*32 + (nt&1)*16 + la);
      Bx[nt] = *(const half8*)(wih16 + grow*FF + wk*32 + lq*8);
    }

  float ebv[8], wxv[8], fcwv[2];
  #pragma unroll
  for (int g = 0; g < 4; g++)
    #pragma unroll
    for (int u = 0; u < 2; u++){
      int jg = jblk*32 + 2*q + u;
      ebv[g*2+u] = ebih[g*HH + jg] + ebhh[g*HH + jg];
      wxv[g*2+u] = 0.f;
    }
  fcwv[0] = fcwv[1] = 0.f;
  const float fcb0v = fcb[0];

  if (jblk == 0 && tid < 16) out[(size_t)(btile*16 + tid)*TT] = 0.f;

  // ---- publish XCC_ID, then the initial counter barrier (arrive's vmcnt(0)
  // drains the publish; full-wait -> all 32 peers' entries visible) ----
  unsigned xcc;
  asm volatile("s_getreg_b32 %0, hwreg(HW_REG_XCC_ID)" : "=s"(xcc));
  if (tid == 0) astoreu(&xcdtab[btile*NJB + jblk], xcc + 1u);

  unsigned* ctr = barctr + btile*32;   // 4 counters used; 128B line per btile
  unsigned barno = 0;
  uint4v snap{};
  barc_arrive(ctr, jblk >> 3, &barno, snap);
  barc_wait(ctr, barno, wk, /*full=*/true, snap, &s_pass);

  if (tid < 64){
    unsigned ent = 1u;
    if (tid < NJB) ent = aloadu(&xcdtab[btile*NJB + tid]);
    unsigned ref = __shfl(ent, 0, 64);
    bool ok = (tid < NJB) ? (ent == ref && ent != 0u) : true;
    unsigned long long bal = __ballot(ok);
    if (tid == 0) s_loc = (bal == ~0ull) ? 1 : 0;
  }
  __syncthreads();

  if (s_loc)
    run_loop<true >(tid, btile, jblk, barno, tgt, src16T, dwhh16, dWih, dbih, dbhh,
                    fcW, fcb0v, out, h16u, ppsl, ctr, Bh, Bx, ebv, wxv, fcwv,
                    Ct4, xacc, predsum, snap, &s_pass);
  else
    run_loop<false>(tid, btile, jblk, barno, tgt, src16T, dwhh16, dWih, dbih, dbhh,
                    fcW, fcb0v, out, h16u, ppsl, ctr, Bh, Bx, ebv, wxv, fcwv,
                    Ct4, xacc, predsum, snap, &s_pass);
}

extern "C" void kernel_launch(void* const* d_in, const int* in_sizes, int n_in,
                              void* d_out, int out_size, void* d_ws, size_t ws_size,
                              hipStream_t stream){
  (void)in_sizes; (void)n_in; (void)out_size; (void)ws_size;
  const float* src  = (const float*)d_in[0];
  const float* tgt  = (const float*)d_in[1];
  const float* eWih = (const float*)d_in[2];
  const float* eWhh = (const float*)d_in[3];
  const float* ebih = (const float*)d_in[4];
  const float* ebhh = (const float*)d_in[5];
  const float* dWih = (const float*)d_in[6];
  const float* dWhh = (const float*)d_in[7];
  const float* dbih = (const float*)d_in[8];
  const float* dbhh = (const float*)d_in[9];
  const float* fcW  = (const float*)d_in[10];
  const float* fcb  = (const float*)d_in[11];
  float* out = (float*)d_out;

  // ws carve (ushort units)
  ushort* h16    = (ushort*)d_ws;          // 2*8*128*16*8     = 262144
  ushort* src16T = h16    + 262144;        // 512*8*128*8      = 4194304
  ushort* wih16  = src16T + 4194304;       // 4096*64          = 262144
  ushort* ewhh16 = wih16  + 262144;        // 4096*1024        = 4194304
  ushort* dwhh16 = ewhh16 + 4194304;       // 4096*1024        = 4194304
  float*  ppsl   = (float*)(dwhh16 + 4194304);     // 2*8*32*16 = 8192 floats
  unsigned* barctr = (unsigned*)(ppsl + 8192);     // 8 btiles x 32 u32 (128B/btile)
  unsigned* xcdtab = barctr + NBT*NJB;             // 8 x 32 u32

  hipMemsetAsync(barctr, 0, 2*NBT*NJB*sizeof(unsigned), stream);
  cvt_src  <<<4096, 256, 0, stream>>>(src, src16T);
  cvt_plain<<<1024, 256, 0, stream>>>(eWih, wih16,  4*HH*FF);
  cvt_plain<<<4096, 256, 0, stream>>>(eWhh, ewhh16, 4*HH*HH);
  cvt_plain<<<4096, 256, 0, stream>>>(dWhh, dwhh16, 4*HH*HH);
  seq_kernel<<<dim3(NBLK), dim3(NTHR), 0, stream>>>(
      tgt, (const _Float16*)src16T, (const _Float16*)wih16,
      (const _Float16*)ewhh16, (const _Float16*)dwhh16,
      ebih, ebhh, dWih, dbih, dbhh, fcW, fcb, out, h16, ppsl, barctr,
      xcdtab);
}